// Round 17
// baseline (50484.879 us; speedup 1.0000x reference)
//
#include <hip/hip_runtime.h>
#include <cmath>

#define NB   256
#define NT   64
#define DATA 256
#define DD   264
#define NSUB 4
#define NTH  512
#define NW   8
#define PI_F 3.14159265358979323846f

// ---- d_ws u32 offsets: bf16-pair packed, k-major. u32 index m = cols (2m,2m+1)
#define WS_W0B  0                        // [272][128] W0T (rows k>=264 zero)
#define WS_W1B  (WS_W0B + 272 * 128)     // [256][128] W1T
#define WS_W2B  (WS_W1B + 256 * 128)     // [256][128] W2T
#define WS_W3B  (WS_W2B + 256 * 128)     // [256][136] W3T cols 0..271 (>=264 zero)

// ---- LDS word offsets ----
#define L_W1B  0                         // [256][128] u32 bf16 W1T = 128 KB
#define L_PS   (L_W1B + 256 * 128)       // fp32 [8][272]
#define L_Y    (L_PS + NW * 272)         // 272 (pads 0)
#define L_IN   (L_Y + 272)               // 272 (pads 0)
#define L_ACC  (L_IN + 272)
#define L_HA   (L_ACC + 272)
#define L_HB   (L_HA + 272)
#define L_B0   (L_HB + 272)              // 256
#define L_B1   (L_B0 + 256)              // 256
#define L_B2   (L_B1 + 256)              // 256
#define L_B3   (L_B2 + 256)              // 272
#define LDS_WORDS (L_B3 + 272)           // 37344 words = 149,376 B -> 1 block/CU

#define UPK(u, f0, f1)                                                        \
  const float f0 = __uint_as_float((u) << 16);                                \
  const float f1 = __uint_as_float((u) & 0xffff0000u);

__device__ __forceinline__ unsigned bf16rn(float f) {
  unsigned u = __float_as_uint(f);
  return (u + 0x7fffu + ((u >> 16) & 1u)) >> 16;   // RNE
}
__device__ __forceinline__ unsigned pk2(float lo, float hi) {
  return bf16rn(lo) | (bf16rn(hi) << 16);
}

__global__ void prep(const float* __restrict__ W0, const float* __restrict__ W1,
                     const float* __restrict__ W2, const float* __restrict__ W3,
                     unsigned* __restrict__ wsu) {
  int tid = blockIdx.x * blockDim.x + threadIdx.x;
  int stride = gridDim.x * blockDim.x;
  for (int i = tid; i < 272 * 128; i += stride) {     // W0T
    int k = i >> 7, m = i & 127;
    float lo = 0.f, hi = 0.f;
    if (k < DD) { lo = W0[(2 * m) * DD + k]; hi = W0[(2 * m + 1) * DD + k]; }
    wsu[WS_W0B + i] = pk2(lo, hi);
  }
  for (int i = tid; i < 256 * 128; i += stride) {     // W1T, W2T
    int k = i >> 7, m = i & 127;
    wsu[WS_W1B + i] = pk2(W1[(2 * m) * 256 + k], W1[(2 * m + 1) * 256 + k]);
    wsu[WS_W2B + i] = pk2(W2[(2 * m) * 256 + k], W2[(2 * m + 1) * 256 + k]);
  }
  for (int i = tid; i < 256 * 136; i += stride) {     // W3T cols 0..271
    int k = i / 136, m = i - k * 136;
    int j0 = 2 * m, j1 = 2 * m + 1;
    float lo = (j0 < DD) ? W3[j0 * 256 + k] : 0.f;
    float hi = (j1 < DD) ? W3[j1 * 256 + k] : 0.f;
    wsu[WS_W3B + i] = pk2(lo, hi);
  }
}

// NTH=512: compiler's empirical VGPR grant is 128 (it targets 2 blocks/CU
// whatever the launch bounds; 1024thr->64, 512thr->128, 256thr->~224).
// Design demand ~80 regs: no register weight cache; W1 in LDS; W0/W2/W3
// streamed bf16 with 8-deep grouped loads (8 uint2 in flight per wave) to
// break R9's serial-load pattern (~210cy/load, VALUBusy 22%).
__global__ __launch_bounds__(NTH) void node_integrate(
    const float* __restrict__ ts, const float* __restrict__ xs,
    const float* __restrict__ a_sample,
    const float* __restrict__ b0g, const float* __restrict__ b1g,
    const float* __restrict__ b2g, const float* __restrict__ b3g,
    const unsigned* __restrict__ wsu, float* __restrict__ out) {
  extern __shared__ float sm[];
  unsigned* smu = (unsigned*)sm;
  const int b   = blockIdx.x;
  const int tid = threadIdx.x;
  const int w   = tid >> 6;    // wave 0..7
  const int l   = tid & 63;    // lane

  // ---- one-time fills ----
  for (int i = tid; i < 256; i += NTH) {
    sm[L_B0 + i] = b0g[i];
    sm[L_B1 + i] = b1g[i];
    sm[L_B2 + i] = b2g[i];
  }
  for (int i = tid; i < 272; i += NTH) sm[L_B3 + i] = (i < DD) ? b3g[i] : 0.f;
  {
    const uint4* src = (const uint4*)(wsu + WS_W1B);
    uint4* dst = (uint4*)(smu + L_W1B);
    for (int i = tid; i < 256 * 32; i += NTH) dst[i] = src[i];
  }
  {
    const float sc = a_sample[b] * expf(-0.1f * ts[0]);
    for (int i = tid; i < 272; i += NTH) {
      float v = 0.f;
      if (i < DATA) v = sc * sinf(PI_F * xs[(size_t)b * DATA + i]);
      sm[L_Y + i]  = v;
      sm[L_IN + i] = 0.f;
    }
  }
  __syncthreads();

  if (tid < DATA) out[((size_t)b * NT) * DATA + tid] = sm[L_Y + tid];

  float4* ps4 = (float4*)(sm + L_PS);                 // [8] rows of 68 float4
  const uint2* w0b2 = (const uint2*)(wsu + WS_W0B);   // [272][64] uint2
  const uint2* w2b2 = (const uint2*)(wsu + WS_W2B);   // [256][64] uint2
  const uint2* w3b2 = (const uint2*)(wsu + WS_W3B);   // [256][68] uint2
  const uint2* w1l2 = (const uint2*)(smu + L_W1B);    // LDS [256][64] uint2

#pragma unroll 1
  for (int t = 0; t < NT - 1; ++t) {
    const float dt = ts[t + 1] - ts[t];
    const float h  = dt * (1.0f / NSUB);
#pragma unroll 1
    for (int sub = 0; sub < NSUB; ++sub) {
#pragma unroll 1
      for (int st = 0; st < 3; ++st) {
        const float* finp = sm + ((st == 0) ? L_Y : L_IN);

        // ---- L0: hA = tanh(W0 @ fin + b0); streamed bf16, K=272(pad)
        // 8-deep load groups: 8 independent uint2 loads issued before use.
        {
          float4 acc; acc.x = acc.y = acc.z = acc.w = 0.f;
          uint2 buf[8]; float fkb[8];
#pragma unroll
          for (int g = 0; g < 40; g += 8) {
            const int G = (34 - g < 8) ? (34 - g) : 8;   // 8,8,8,8,2
#pragma unroll
            for (int j = 0; j < G; ++j) {
              const int k = w + 8 * (g + j);             // < 272
              buf[j] = w0b2[k * 64 + l];
              fkb[j] = finp[k];
            }
#pragma unroll
            for (int j = 0; j < G; ++j) {
              UPK(buf[j].x, c0, c1) UPK(buf[j].y, c2, c3)
              const float fk = fkb[j];
              acc.x = fmaf(c0, fk, acc.x); acc.y = fmaf(c1, fk, acc.y);
              acc.z = fmaf(c2, fk, acc.z); acc.w = fmaf(c3, fk, acc.w);
            }
          }
          ps4[w * 68 + l] = acc;
        }
        __syncthreads();
        if (tid < 256) {
          float sv = sm[L_B0 + tid];
#pragma unroll
          for (int ww = 0; ww < NW; ++ww) sv += sm[L_PS + ww * 272 + tid];
          sm[L_HA + tid] = tanhf(sv);
        }
        __syncthreads();

        // ---- L1: hB = tanh(W1 @ hA + b1); all from LDS bf16
        {
          float4 acc; acc.x = acc.y = acc.z = acc.w = 0.f;
#pragma unroll
          for (int i = 0; i < 32; ++i) {
            const int k = w + 8 * i;           // < 256
            const uint2 u = w1l2[k * 64 + l];
            const float fk = sm[L_HA + k];
            UPK(u.x, c0, c1) UPK(u.y, c2, c3)
            acc.x = fmaf(c0, fk, acc.x); acc.y = fmaf(c1, fk, acc.y);
            acc.z = fmaf(c2, fk, acc.z); acc.w = fmaf(c3, fk, acc.w);
          }
          ps4[w * 68 + l] = acc;
        }
        __syncthreads();
        if (tid < 256) {
          float sv = sm[L_B1 + tid];
#pragma unroll
          for (int ww = 0; ww < NW; ++ww) sv += sm[L_PS + ww * 272 + tid];
          sm[L_HB + tid] = tanhf(sv);
        }
        __syncthreads();

        // ---- L2: hA = tanh(W2 @ hB + b2); streamed bf16, grouped loads
        {
          float4 acc; acc.x = acc.y = acc.z = acc.w = 0.f;
          uint2 buf[8]; float fkb[8];
#pragma unroll
          for (int g = 0; g < 32; g += 8) {
#pragma unroll
            for (int j = 0; j < 8; ++j) {
              const int k = w + 8 * (g + j);   // < 256
              buf[j] = w2b2[k * 64 + l];
              fkb[j] = sm[L_HB + k];
            }
#pragma unroll
            for (int j = 0; j < 8; ++j) {
              UPK(buf[j].x, c0, c1) UPK(buf[j].y, c2, c3)
              const float fk = fkb[j];
              acc.x = fmaf(c0, fk, acc.x); acc.y = fmaf(c1, fk, acc.y);
              acc.z = fmaf(c2, fk, acc.z); acc.w = fmaf(c3, fk, acc.w);
            }
          }
          ps4[w * 68 + l] = acc;
        }
        __syncthreads();
        if (tid < 256) {
          float sv = sm[L_B2 + tid];
#pragma unroll
          for (int ww = 0; ww < NW; ++ww) sv += sm[L_PS + ww * 272 + tid];
          sm[L_HA + tid] = tanhf(sv);
        }
        __syncthreads();

        // ---- L3: kv = W3 @ hA + b3; streamed bf16, grouped loads
        {
          float4 acc;  acc.x = acc.y = acc.z = acc.w = 0.f;
          float4 accx; accx.x = accx.y = accx.z = accx.w = 0.f;
          uint2 buf[8]; float fkb[8];
#pragma unroll
          for (int g = 0; g < 32; g += 8) {
#pragma unroll
            for (int j = 0; j < 8; ++j) {
              const int k = w + 8 * (g + j);
              buf[j] = w3b2[k * 68 + l];               // cols 4l..4l+3
              fkb[j] = sm[L_HA + k];
            }
#pragma unroll
            for (int j = 0; j < 8; ++j) {
              UPK(buf[j].x, c0, c1) UPK(buf[j].y, c2, c3)
              const float fk = fkb[j];
              acc.x = fmaf(c0, fk, acc.x); acc.y = fmaf(c1, fk, acc.y);
              acc.z = fmaf(c2, fk, acc.z); acc.w = fmaf(c3, fk, acc.w);
            }
          }
          if (l < 4) {
#pragma unroll
            for (int i = 0; i < 32; ++i) {
              const int k = w + 8 * i;
              const float fk = sm[L_HA + k];
              const uint2 ux = w3b2[k * 68 + 64 + l];  // cols 256..271
              UPK(ux.x, d0, d1) UPK(ux.y, d2, d3)
              accx.x = fmaf(d0, fk, accx.x); accx.y = fmaf(d1, fk, accx.y);
              accx.z = fmaf(d2, fk, accx.z); accx.w = fmaf(d3, fk, accx.w);
            }
          }
          ps4[w * 68 + l] = acc;
          if (l < 4) ps4[w * 68 + 64 + l] = accx;
        }
        __syncthreads();
        if (tid < DD) {
          float kv = sm[L_B3 + tid];
#pragma unroll
          for (int ww = 0; ww < NW; ++ww) kv += sm[L_PS + ww * 272 + tid];
          if (st == 0) {
            sm[L_ACC + tid] = (2.0f / 9.0f) * kv;
            sm[L_IN + tid]  = sm[L_Y + tid] + 0.5f * h * kv;
          } else if (st == 1) {
            sm[L_ACC + tid] += (1.0f / 3.0f) * kv;
            sm[L_IN + tid]   = sm[L_Y + tid] + 0.75f * h * kv;
          } else {
            sm[L_Y + tid] += h * (sm[L_ACC + tid] + (4.0f / 9.0f) * kv);
          }
        }
        __syncthreads();
      }
    }
    if (tid < DATA) out[((size_t)b * NT + (t + 1)) * DATA + tid] = sm[L_Y + tid];
  }
}

extern "C" void kernel_launch(void* const* d_in, const int* in_sizes, int n_in,
                              void* d_out, int out_size, void* d_ws, size_t ws_size,
                              hipStream_t stream) {
  const float* ts = (const float*)d_in[0];
  const float* xs = (const float*)d_in[1];
  const float* a  = (const float*)d_in[2];
  const float* W0 = (const float*)d_in[3];
  const float* b0 = (const float*)d_in[4];
  const float* W1 = (const float*)d_in[5];
  const float* b1 = (const float*)d_in[6];
  const float* W2 = (const float*)d_in[7];
  const float* b2 = (const float*)d_in[8];
  const float* W3 = (const float*)d_in[9];
  const float* b3 = (const float*)d_in[10];
  unsigned* ws = (unsigned*)d_ws;
  float* out = (float*)d_out;

  const size_t lds_bytes = LDS_WORDS * sizeof(float);
  hipFuncSetAttribute(reinterpret_cast<const void*>(node_integrate),
                      hipFuncAttributeMaxDynamicSharedMemorySize,
                      (int)lds_bytes);

  hipLaunchKernelGGL(prep, dim3(256), dim3(256), 0, stream, W0, W1, W2, W3, ws);
  hipLaunchKernelGGL(node_integrate, dim3(NB), dim3(NTH), lds_bytes, stream,
                     ts, xs, a, b0, b1, b2, b3, ws, out);
}

// Round 18
// 47211.667 us; speedup vs baseline: 1.0693x; 1.0693x over previous
//
#include <hip/hip_runtime.h>
#include <cmath>

#define NB   256
#define NT   64
#define DATA 256
#define DD   264
#define NSUB 4
#define NTH  512
#define NW   8
#define PI_F 3.14159265358979323846f

// ---- d_ws u32 offsets: bf16-pair packed, k-major. u32 index m = cols (2m,2m+1)
#define WS_W0B  0                        // [272][128] W0T (rows k>=264 zero)
#define WS_W1B  (WS_W0B + 272 * 128)     // [256][128] W1T
#define WS_W2B  (WS_W1B + 256 * 128)     // [256][128] W2T
#define WS_W3B  (WS_W2B + 256 * 128)     // [256][136] W3T cols 0..271 (>=264 zero)

// ---- LDS word offsets ----
#define L_W1B  0                         // [256][128] u32 bf16 W1T = 128 KB
#define L_PS   (L_W1B + 256 * 128)       // fp32 [8][272]
#define L_Y    (L_PS + NW * 272)         // 272 (pads 0)
#define L_IN   (L_Y + 272)               // 272 (pads 0)
#define L_ACC  (L_IN + 272)
#define L_HA   (L_ACC + 272)
#define L_HB   (L_HA + 272)
#define L_B0   (L_HB + 272)              // 256
#define L_B1   (L_B0 + 256)              // 256
#define L_B2   (L_B1 + 256)              // 256
#define L_B3   (L_B2 + 256)              // 272
#define LDS_WORDS (L_B3 + 272)           // 37344 words = 149,376 B -> 1 block/CU

#define UPK(u, f0, f1)                                                        \
  const float f0 = __uint_as_float((u) << 16);                                \
  const float f1 = __uint_as_float((u) & 0xffff0000u);

__device__ __forceinline__ unsigned bf16rn(float f) {
  unsigned u = __float_as_uint(f);
  return (u + 0x7fffu + ((u >> 16) & 1u)) >> 16;   // RNE
}
__device__ __forceinline__ unsigned pk2(float lo, float hi) {
  return bf16rn(lo) | (bf16rn(hi) << 16);
}

__global__ void prep(const float* __restrict__ W0, const float* __restrict__ W1,
                     const float* __restrict__ W2, const float* __restrict__ W3,
                     unsigned* __restrict__ wsu) {
  int tid = blockIdx.x * blockDim.x + threadIdx.x;
  int stride = gridDim.x * blockDim.x;
  for (int i = tid; i < 272 * 128; i += stride) {     // W0T
    int k = i >> 7, m = i & 127;
    float lo = 0.f, hi = 0.f;
    if (k < DD) { lo = W0[(2 * m) * DD + k]; hi = W0[(2 * m + 1) * DD + k]; }
    wsu[WS_W0B + i] = pk2(lo, hi);
  }
  for (int i = tid; i < 256 * 128; i += stride) {     // W1T, W2T
    int k = i >> 7, m = i & 127;
    wsu[WS_W1B + i] = pk2(W1[(2 * m) * 256 + k], W1[(2 * m + 1) * 256 + k]);
    wsu[WS_W2B + i] = pk2(W2[(2 * m) * 256 + k], W2[(2 * m + 1) * 256 + k]);
  }
  for (int i = tid; i < 256 * 136; i += stride) {     // W3T cols 0..271
    int k = i / 136, m = i - k * 136;
    int j0 = 2 * m, j1 = 2 * m + 1;
    float lo = (j0 < DD) ? W3[j0 * 256 + k] : 0.f;
    float hi = (j1 < DD) ? W3[j1 * 256 + k] : 0.f;
    wsu[WS_W3B + i] = pk2(lo, hi);
  }
}

// R18 = union of all proven-good pieces:
//  - simple per-iteration loads (R9/R10: L2-resident, FETCH ~5MB; R14's
//    grouped-load buffers spilled -> scratch polluted L2 -> 67GB HBM fetch)
//  - NO register weight caches (every attempt spilled; scratch = L2 poison)
//  - W1 fully in LDS bf16 (zero L1 stream); W0/W2/W3 streamed bf16
//  - R14's W3 column-pad tail (0 bank conflicts measured), R9's PS-reduce
__global__ __launch_bounds__(NTH) void node_integrate(
    const float* __restrict__ ts, const float* __restrict__ xs,
    const float* __restrict__ a_sample,
    const float* __restrict__ b0g, const float* __restrict__ b1g,
    const float* __restrict__ b2g, const float* __restrict__ b3g,
    const unsigned* __restrict__ wsu, float* __restrict__ out) {
  extern __shared__ float sm[];
  unsigned* smu = (unsigned*)sm;
  const int b   = blockIdx.x;
  const int tid = threadIdx.x;
  const int w   = tid >> 6;    // wave 0..7
  const int l   = tid & 63;    // lane

  // ---- one-time fills ----
  for (int i = tid; i < 256; i += NTH) {
    sm[L_B0 + i] = b0g[i];
    sm[L_B1 + i] = b1g[i];
    sm[L_B2 + i] = b2g[i];
  }
  for (int i = tid; i < 272; i += NTH) sm[L_B3 + i] = (i < DD) ? b3g[i] : 0.f;
  {
    const uint4* src = (const uint4*)(wsu + WS_W1B);
    uint4* dst = (uint4*)(smu + L_W1B);
    for (int i = tid; i < 256 * 32; i += NTH) dst[i] = src[i];
  }
  {
    const float sc = a_sample[b] * expf(-0.1f * ts[0]);
    for (int i = tid; i < 272; i += NTH) {
      float v = 0.f;
      if (i < DATA) v = sc * sinf(PI_F * xs[(size_t)b * DATA + i]);
      sm[L_Y + i]  = v;
      sm[L_IN + i] = 0.f;
    }
  }
  __syncthreads();

  if (tid < DATA) out[((size_t)b * NT) * DATA + tid] = sm[L_Y + tid];

  float4* ps4 = (float4*)(sm + L_PS);                 // [8] rows of 68 float4
  const uint2* w0b2 = (const uint2*)(wsu + WS_W0B);   // [272][64] uint2
  const uint2* w2b2 = (const uint2*)(wsu + WS_W2B);   // [256][64] uint2
  const uint2* w3b2 = (const uint2*)(wsu + WS_W3B);   // [256][68] uint2
  const uint2* w1l2 = (const uint2*)(smu + L_W1B);    // LDS [256][64] uint2

#pragma unroll 1
  for (int t = 0; t < NT - 1; ++t) {
    const float dt = ts[t + 1] - ts[t];
    const float h  = dt * (1.0f / NSUB);
#pragma unroll 1
    for (int sub = 0; sub < NSUB; ++sub) {
#pragma unroll 1
      for (int st = 0; st < 3; ++st) {
        const float* finp = sm + ((st == 0) ? L_Y : L_IN);

        // ---- L0: hA = tanh(W0 @ fin + b0); streamed bf16, K=272(pad)
        {
          float4 acc; acc.x = acc.y = acc.z = acc.w = 0.f;
#pragma unroll
          for (int i = 0; i < 34; ++i) {
            const int k = w + 8 * i;            // < 272
            const uint2 u = w0b2[k * 64 + l];   // cols 4l..4l+3
            const float fk = finp[k];
            UPK(u.x, c0, c1) UPK(u.y, c2, c3)
            acc.x = fmaf(c0, fk, acc.x); acc.y = fmaf(c1, fk, acc.y);
            acc.z = fmaf(c2, fk, acc.z); acc.w = fmaf(c3, fk, acc.w);
          }
          ps4[w * 68 + l] = acc;
        }
        __syncthreads();
        if (tid < 256) {
          float sv = sm[L_B0 + tid];
#pragma unroll
          for (int ww = 0; ww < NW; ++ww) sv += sm[L_PS + ww * 272 + tid];
          sm[L_HA + tid] = tanhf(sv);
        }
        __syncthreads();

        // ---- L1: hB = tanh(W1 @ hA + b1); all from LDS bf16
        {
          float4 acc; acc.x = acc.y = acc.z = acc.w = 0.f;
#pragma unroll
          for (int i = 0; i < 32; ++i) {
            const int k = w + 8 * i;           // < 256
            const uint2 u = w1l2[k * 64 + l];
            const float fk = sm[L_HA + k];
            UPK(u.x, c0, c1) UPK(u.y, c2, c3)
            acc.x = fmaf(c0, fk, acc.x); acc.y = fmaf(c1, fk, acc.y);
            acc.z = fmaf(c2, fk, acc.z); acc.w = fmaf(c3, fk, acc.w);
          }
          ps4[w * 68 + l] = acc;
        }
        __syncthreads();
        if (tid < 256) {
          float sv = sm[L_B1 + tid];
#pragma unroll
          for (int ww = 0; ww < NW; ++ww) sv += sm[L_PS + ww * 272 + tid];
          sm[L_HB + tid] = tanhf(sv);
        }
        __syncthreads();

        // ---- L2: hA = tanh(W2 @ hB + b2); streamed bf16
        {
          float4 acc; acc.x = acc.y = acc.z = acc.w = 0.f;
#pragma unroll
          for (int i = 0; i < 32; ++i) {
            const int k = w + 8 * i;           // < 256
            const uint2 u = w2b2[k * 64 + l];
            const float fk = sm[L_HB + k];
            UPK(u.x, c0, c1) UPK(u.y, c2, c3)
            acc.x = fmaf(c0, fk, acc.x); acc.y = fmaf(c1, fk, acc.y);
            acc.z = fmaf(c2, fk, acc.z); acc.w = fmaf(c3, fk, acc.w);
          }
          ps4[w * 68 + l] = acc;
        }
        __syncthreads();
        if (tid < 256) {
          float sv = sm[L_B2 + tid];
#pragma unroll
          for (int ww = 0; ww < NW; ++ww) sv += sm[L_PS + ww * 272 + tid];
          sm[L_HA + tid] = tanhf(sv);
        }
        __syncthreads();

        // ---- L3: kv = W3 @ hA + b3; streamed bf16 [256][68] uint2 rows
        {
          float4 acc;  acc.x = acc.y = acc.z = acc.w = 0.f;
          float4 accx; accx.x = accx.y = accx.z = accx.w = 0.f;
#pragma unroll
          for (int i = 0; i < 32; ++i) {
            const int k = w + 8 * i;
            const float fk = sm[L_HA + k];
            const uint2 u = w3b2[k * 68 + l];            // cols 4l..4l+3
            UPK(u.x, c0, c1) UPK(u.y, c2, c3)
            acc.x = fmaf(c0, fk, acc.x); acc.y = fmaf(c1, fk, acc.y);
            acc.z = fmaf(c2, fk, acc.z); acc.w = fmaf(c3, fk, acc.w);
          }
          if (l < 4) {
#pragma unroll
            for (int i = 0; i < 32; ++i) {
              const int k = w + 8 * i;
              const float fk = sm[L_HA + k];
              const uint2 ux = w3b2[k * 68 + 64 + l];    // cols 256..271
              UPK(ux.x, d0, d1) UPK(ux.y, d2, d3)
              accx.x = fmaf(d0, fk, accx.x); accx.y = fmaf(d1, fk, accx.y);
              accx.z = fmaf(d2, fk, accx.z); accx.w = fmaf(d3, fk, accx.w);
            }
          }
          ps4[w * 68 + l] = acc;
          if (l < 4) ps4[w * 68 + 64 + l] = accx;
        }
        __syncthreads();
        if (tid < DD) {
          float kv = sm[L_B3 + tid];
#pragma unroll
          for (int ww = 0; ww < NW; ++ww) kv += sm[L_PS + ww * 272 + tid];
          if (st == 0) {
            sm[L_ACC + tid] = (2.0f / 9.0f) * kv;
            sm[L_IN + tid]  = sm[L_Y + tid] + 0.5f * h * kv;
          } else if (st == 1) {
            sm[L_ACC + tid] += (1.0f / 3.0f) * kv;
            sm[L_IN + tid]   = sm[L_Y + tid] + 0.75f * h * kv;
          } else {
            sm[L_Y + tid] += h * (sm[L_ACC + tid] + (4.0f / 9.0f) * kv);
          }
        }
        __syncthreads();
      }
    }
    if (tid < DATA) out[((size_t)b * NT + (t + 1)) * DATA + tid] = sm[L_Y + tid];
  }
}

extern "C" void kernel_launch(void* const* d_in, const int* in_sizes, int n_in,
                              void* d_out, int out_size, void* d_ws, size_t ws_size,
                              hipStream_t stream) {
  const float* ts = (const float*)d_in[0];
  const float* xs = (const float*)d_in[1];
  const float* a  = (const float*)d_in[2];
  const float* W0 = (const float*)d_in[3];
  const float* b0 = (const float*)d_in[4];
  const float* W1 = (const float*)d_in[5];
  const float* b1 = (const float*)d_in[6];
  const float* W2 = (const float*)d_in[7];
  const float* b2 = (const float*)d_in[8];
  const float* W3 = (const float*)d_in[9];
  const float* b3 = (const float*)d_in[10];
  unsigned* ws = (unsigned*)d_ws;
  float* out = (float*)d_out;

  const size_t lds_bytes = LDS_WORDS * sizeof(float);
  hipFuncSetAttribute(reinterpret_cast<const void*>(node_integrate),
                      hipFuncAttributeMaxDynamicSharedMemorySize,
                      (int)lds_bytes);

  hipLaunchKernelGGL(prep, dim3(256), dim3(256), 0, stream, W0, W1, W2, W3, ws);
  hipLaunchKernelGGL(node_integrate, dim3(NB), dim3(NTH), lds_bytes, stream,
                     ts, xs, a, b0, b1, b2, b3, ws, out);
}

// Round 19
// 13229.575 us; speedup vs baseline: 3.8161x; 3.5686x over previous
//
#include <hip/hip_runtime.h>
#include <cmath>

#define NB   256
#define NT   64
#define DATA 256
#define DD   264
#define NSUB 4
#define NTH  512
#define NW   8
#define PI_F 3.14159265358979323846f

// ---- d_ws u32 offsets: bf16-pair packed, k-major. u32 index m = cols (2m,2m+1)
#define WS_W0B  0                        // [272][128] W0T (rows k>=264 zero)
#define WS_W1B  (WS_W0B + 272 * 128)     // [256][128] W1T
#define WS_W2B  (WS_W1B + 256 * 128)     // [256][128] W2T
#define WS_W3B  (WS_W2B + 256 * 128)     // [256][136] W3T cols 0..271 (>=264 zero)

// ---- LDS word offsets ----
#define L_W1B  0                         // [256][128] u32 bf16 W1T = 128 KB
#define L_PS   (L_W1B + 256 * 128)       // fp32 [8][272]
#define L_Y    (L_PS + NW * 272)         // 272 (pads 0)
#define L_IN   (L_Y + 272)               // 272 (pads 0)
#define L_ACC  (L_IN + 272)
#define L_HA   (L_ACC + 272)
#define L_HB   (L_HA + 272)
#define L_B0   (L_HB + 272)              // 256
#define L_B1   (L_B0 + 256)              // 256
#define L_B2   (L_B1 + 256)              // 256
#define L_B3   (L_B2 + 256)              // 272
#define LDS_WORDS (L_B3 + 272)           // 37344 words = 149,376 B -> 1 block/CU

#define UPK(u, f0, f1)                                                        \
  const float f0 = __uint_as_float((u) << 16);                                \
  const float f1 = __uint_as_float((u) & 0xffff0000u);

__device__ __forceinline__ unsigned bf16rn(float f) {
  unsigned u = __float_as_uint(f);
  return (u + 0x7fffu + ((u >> 16) & 1u)) >> 16;   // RNE
}
__device__ __forceinline__ unsigned pk2(float lo, float hi) {
  return bf16rn(lo) | (bf16rn(hi) << 16);
}

__global__ void prep(const float* __restrict__ W0, const float* __restrict__ W1,
                     const float* __restrict__ W2, const float* __restrict__ W3,
                     unsigned* __restrict__ wsu) {
  int tid = blockIdx.x * blockDim.x + threadIdx.x;
  int stride = gridDim.x * blockDim.x;
  for (int i = tid; i < 272 * 128; i += stride) {     // W0T
    int k = i >> 7, m = i & 127;
    float lo = 0.f, hi = 0.f;
    if (k < DD) { lo = W0[(2 * m) * DD + k]; hi = W0[(2 * m + 1) * DD + k]; }
    wsu[WS_W0B + i] = pk2(lo, hi);
  }
  for (int i = tid; i < 256 * 128; i += stride) {     // W1T, W2T
    int k = i >> 7, m = i & 127;
    wsu[WS_W1B + i] = pk2(W1[(2 * m) * 256 + k], W1[(2 * m + 1) * 256 + k]);
    wsu[WS_W2B + i] = pk2(W2[(2 * m) * 256 + k], W2[(2 * m + 1) * 256 + k]);
  }
  for (int i = tid; i < 256 * 136; i += stride) {     // W3T cols 0..271
    int k = i / 136, m = i - k * 136;
    int j0 = 2 * m, j1 = 2 * m + 1;
    float lo = (j0 < DD) ? W3[j0 * 256 + k] : 0.f;
    float hi = (j1 < DD) ? W3[j1 * 256 + k] : 0.f;
    wsu[WS_W3B + i] = pk2(lo, hi);
  }
}

// R19 = R18 with BOUNDED unroll on stream loops. Full `#pragma unroll`
// makes the compiler hoist ALL loads to the loop head (34 uint2 + 34 fk
// ~ 100+ regs in flight) -> exceeds the 128-reg grant -> wholesale spill
// (R13/R14/R17/R18: WRITE 250-490MB, FETCH 60-80GB). R9 (unroll 4) and
// R10 (unroll 8) ran clean: FETCH ~5MB, WRITE ~17-21MB. unroll 4 = ~8
// loads in flight per wave, under budget, latency still covered.
__global__ __launch_bounds__(NTH) void node_integrate(
    const float* __restrict__ ts, const float* __restrict__ xs,
    const float* __restrict__ a_sample,
    const float* __restrict__ b0g, const float* __restrict__ b1g,
    const float* __restrict__ b2g, const float* __restrict__ b3g,
    const unsigned* __restrict__ wsu, float* __restrict__ out) {
  extern __shared__ float sm[];
  unsigned* smu = (unsigned*)sm;
  const int b   = blockIdx.x;
  const int tid = threadIdx.x;
  const int w   = tid >> 6;    // wave 0..7
  const int l   = tid & 63;    // lane

  // ---- one-time fills ----
  for (int i = tid; i < 256; i += NTH) {
    sm[L_B0 + i] = b0g[i];
    sm[L_B1 + i] = b1g[i];
    sm[L_B2 + i] = b2g[i];
  }
  for (int i = tid; i < 272; i += NTH) sm[L_B3 + i] = (i < DD) ? b3g[i] : 0.f;
  {
    const uint4* src = (const uint4*)(wsu + WS_W1B);
    uint4* dst = (uint4*)(smu + L_W1B);
    for (int i = tid; i < 256 * 32; i += NTH) dst[i] = src[i];
  }
  {
    const float sc = a_sample[b] * expf(-0.1f * ts[0]);
    for (int i = tid; i < 272; i += NTH) {
      float v = 0.f;
      if (i < DATA) v = sc * sinf(PI_F * xs[(size_t)b * DATA + i]);
      sm[L_Y + i]  = v;
      sm[L_IN + i] = 0.f;
    }
  }
  __syncthreads();

  if (tid < DATA) out[((size_t)b * NT) * DATA + tid] = sm[L_Y + tid];

  float4* ps4 = (float4*)(sm + L_PS);                 // [8] rows of 68 float4
  const uint2* w0b2 = (const uint2*)(wsu + WS_W0B);   // [272][64] uint2
  const uint2* w2b2 = (const uint2*)(wsu + WS_W2B);   // [256][64] uint2
  const uint2* w3b2 = (const uint2*)(wsu + WS_W3B);   // [256][68] uint2
  const uint2* w1l2 = (const uint2*)(smu + L_W1B);    // LDS [256][64] uint2

#pragma unroll 1
  for (int t = 0; t < NT - 1; ++t) {
    const float dt = ts[t + 1] - ts[t];
    const float h  = dt * (1.0f / NSUB);
#pragma unroll 1
    for (int sub = 0; sub < NSUB; ++sub) {
#pragma unroll 1
      for (int st = 0; st < 3; ++st) {
        const float* finp = sm + ((st == 0) ? L_Y : L_IN);

        // ---- L0: hA = tanh(W0 @ fin + b0); streamed bf16, K=272(pad)
        {
          float4 acc; acc.x = acc.y = acc.z = acc.w = 0.f;
#pragma unroll 4
          for (int i = 0; i < 34; ++i) {
            const int k = w + 8 * i;            // < 272
            const uint2 u = w0b2[k * 64 + l];   // cols 4l..4l+3
            const float fk = finp[k];
            UPK(u.x, c0, c1) UPK(u.y, c2, c3)
            acc.x = fmaf(c0, fk, acc.x); acc.y = fmaf(c1, fk, acc.y);
            acc.z = fmaf(c2, fk, acc.z); acc.w = fmaf(c3, fk, acc.w);
          }
          ps4[w * 68 + l] = acc;
        }
        __syncthreads();
        if (tid < 256) {
          float sv = sm[L_B0 + tid];
#pragma unroll
          for (int ww = 0; ww < NW; ++ww) sv += sm[L_PS + ww * 272 + tid];
          sm[L_HA + tid] = tanhf(sv);
        }
        __syncthreads();

        // ---- L1: hB = tanh(W1 @ hA + b1); all from LDS bf16
        {
          float4 acc; acc.x = acc.y = acc.z = acc.w = 0.f;
#pragma unroll 8
          for (int i = 0; i < 32; ++i) {
            const int k = w + 8 * i;           // < 256
            const uint2 u = w1l2[k * 64 + l];
            const float fk = sm[L_HA + k];
            UPK(u.x, c0, c1) UPK(u.y, c2, c3)
            acc.x = fmaf(c0, fk, acc.x); acc.y = fmaf(c1, fk, acc.y);
            acc.z = fmaf(c2, fk, acc.z); acc.w = fmaf(c3, fk, acc.w);
          }
          ps4[w * 68 + l] = acc;
        }
        __syncthreads();
        if (tid < 256) {
          float sv = sm[L_B1 + tid];
#pragma unroll
          for (int ww = 0; ww < NW; ++ww) sv += sm[L_PS + ww * 272 + tid];
          sm[L_HB + tid] = tanhf(sv);
        }
        __syncthreads();

        // ---- L2: hA = tanh(W2 @ hB + b2); streamed bf16
        {
          float4 acc; acc.x = acc.y = acc.z = acc.w = 0.f;
#pragma unroll 4
          for (int i = 0; i < 32; ++i) {
            const int k = w + 8 * i;           // < 256
            const uint2 u = w2b2[k * 64 + l];
            const float fk = sm[L_HB + k];
            UPK(u.x, c0, c1) UPK(u.y, c2, c3)
            acc.x = fmaf(c0, fk, acc.x); acc.y = fmaf(c1, fk, acc.y);
            acc.z = fmaf(c2, fk, acc.z); acc.w = fmaf(c3, fk, acc.w);
          }
          ps4[w * 68 + l] = acc;
        }
        __syncthreads();
        if (tid < 256) {
          float sv = sm[L_B2 + tid];
#pragma unroll
          for (int ww = 0; ww < NW; ++ww) sv += sm[L_PS + ww * 272 + tid];
          sm[L_HA + tid] = tanhf(sv);
        }
        __syncthreads();

        // ---- L3: kv = W3 @ hA + b3; streamed bf16 [256][68] uint2 rows
        {
          float4 acc;  acc.x = acc.y = acc.z = acc.w = 0.f;
          float4 accx; accx.x = accx.y = accx.z = accx.w = 0.f;
#pragma unroll 4
          for (int i = 0; i < 32; ++i) {
            const int k = w + 8 * i;
            const float fk = sm[L_HA + k];
            const uint2 u = w3b2[k * 68 + l];            // cols 4l..4l+3
            UPK(u.x, c0, c1) UPK(u.y, c2, c3)
            acc.x = fmaf(c0, fk, acc.x); acc.y = fmaf(c1, fk, acc.y);
            acc.z = fmaf(c2, fk, acc.z); acc.w = fmaf(c3, fk, acc.w);
          }
          if (l < 4) {
#pragma unroll 4
            for (int i = 0; i < 32; ++i) {
              const int k = w + 8 * i;
              const float fk = sm[L_HA + k];
              const uint2 ux = w3b2[k * 68 + 64 + l];    // cols 256..271
              UPK(ux.x, d0, d1) UPK(ux.y, d2, d3)
              accx.x = fmaf(d0, fk, accx.x); accx.y = fmaf(d1, fk, accx.y);
              accx.z = fmaf(d2, fk, accx.z); accx.w = fmaf(d3, fk, accx.w);
            }
          }
          ps4[w * 68 + l] = acc;
          if (l < 4) ps4[w * 68 + 64 + l] = accx;
        }
        __syncthreads();
        if (tid < DD) {
          float kv = sm[L_B3 + tid];
#pragma unroll
          for (int ww = 0; ww < NW; ++ww) kv += sm[L_PS + ww * 272 + tid];
          if (st == 0) {
            sm[L_ACC + tid] = (2.0f / 9.0f) * kv;
            sm[L_IN + tid]  = sm[L_Y + tid] + 0.5f * h * kv;
          } else if (st == 1) {
            sm[L_ACC + tid] += (1.0f / 3.0f) * kv;
            sm[L_IN + tid]   = sm[L_Y + tid] + 0.75f * h * kv;
          } else {
            sm[L_Y + tid] += h * (sm[L_ACC + tid] + (4.0f / 9.0f) * kv);
          }
        }
        __syncthreads();
      }
    }
    if (tid < DATA) out[((size_t)b * NT + (t + 1)) * DATA + tid] = sm[L_Y + tid];
  }
}

extern "C" void kernel_launch(void* const* d_in, const int* in_sizes, int n_in,
                              void* d_out, int out_size, void* d_ws, size_t ws_size,
                              hipStream_t stream) {
  const float* ts = (const float*)d_in[0];
  const float* xs = (const float*)d_in[1];
  const float* a  = (const float*)d_in[2];
  const float* W0 = (const float*)d_in[3];
  const float* b0 = (const float*)d_in[4];
  const float* W1 = (const float*)d_in[5];
  const float* b1 = (const float*)d_in[6];
  const float* W2 = (const float*)d_in[7];
  const float* b2 = (const float*)d_in[8];
  const float* W3 = (const float*)d_in[9];
  const float* b3 = (const float*)d_in[10];
  unsigned* ws = (unsigned*)d_ws;
  float* out = (float*)d_out;

  const size_t lds_bytes = LDS_WORDS * sizeof(float);
  hipFuncSetAttribute(reinterpret_cast<const void*>(node_integrate),
                      hipFuncAttributeMaxDynamicSharedMemorySize,
                      (int)lds_bytes);

  hipLaunchKernelGGL(prep, dim3(256), dim3(256), 0, stream, W0, W1, W2, W3, ws);
  hipLaunchKernelGGL(node_integrate, dim3(NB), dim3(NTH), lds_bytes, stream,
                     ts, xs, a, b0, b1, b2, b3, ws, out);
}

// Round 20
// 5491.369 us; speedup vs baseline: 9.1935x; 2.4092x over previous
//
#include <hip/hip_runtime.h>
#include <cmath>

#define NB   256
#define NT   64
#define DATA 256
#define DD   264
#define NSUB 4
#define NTH  1024
#define NW   16
#define PI_F 3.14159265358979323846f

// ---- d_ws u32 offsets: PAIRED-ROW bf16 packing ----
// uint4 at [kk*64 + l] = { row 2kk cols 4l..4l+3, row 2kk+1 cols 4l..4l+3 }
// u32 j within group of 4: j>>1 selects row (2kk / 2kk+1), (j&1)*2 col offset.
#define WS_W0B 0                        // [136 kk][256 u32]  (K=272 padded)
#define WS_W1B (WS_W0B + 136 * 256)     // [128][256]
#define WS_W2B (WS_W1B + 128 * 256)     // [128][256]
#define WS_W3B (WS_W2B + 128 * 256)     // [128][256]  cols 0..255
#define WS_W3T (WS_W3B + 128 * 256)     // [128][16]   cols 256..271 (>=264 pad 0)

// ---- LDS word offsets ----
#define L_W1B  0                        // [128 kk][256 u32] paired W1 = 128 KB
#define L_PS   (L_W1B + 128 * 256)      // fp32 [16][272]
#define L_Y    (L_PS + NW * 272)        // 272 (pads 0)
#define L_IN   (L_Y + 272)              // 272 (pads 0)
#define L_ACC  (L_IN + 272)
#define L_HA   (L_ACC + 272)
#define L_HB   (L_HA + 272)
#define L_B0   (L_HB + 272)             // 256
#define L_B1   (L_B0 + 256)             // 256
#define L_B2   (L_B1 + 256)             // 256
#define L_B3   (L_B2 + 256)             // 272
#define LDS_WORDS (L_B3 + 272)          // 39520 words = 158,080 B -> 1 block/CU

#define UPK(u, f0, f1)                                                        \
  const float f0 = __uint_as_float((u) << 16);                                \
  const float f1 = __uint_as_float((u) & 0xffff0000u);

// one paired uint4: 8 bf16 (2 rows x 4 cols) -> 8 FMAs into acc with f0/f1
#define FMA8(acc, u, f0, f1)                                                  \
  {                                                                           \
    UPK(u.x, c0, c1) UPK(u.y, c2, c3) UPK(u.z, c4, c5) UPK(u.w, c6, c7)       \
    acc.x = fmaf(c0, f0, acc.x); acc.y = fmaf(c1, f0, acc.y);                 \
    acc.z = fmaf(c2, f0, acc.z); acc.w = fmaf(c3, f0, acc.w);                 \
    acc.x = fmaf(c4, f1, acc.x); acc.y = fmaf(c5, f1, acc.y);                 \
    acc.z = fmaf(c6, f1, acc.z); acc.w = fmaf(c7, f1, acc.w);                 \
  }

__device__ __forceinline__ unsigned bf16rn(float f) {
  unsigned u = __float_as_uint(f);
  return (u + 0x7fffu + ((u >> 16) & 1u)) >> 16;   // RNE
}
__device__ __forceinline__ unsigned pk2(float lo, float hi) {
  return bf16rn(lo) | (bf16rn(hi) << 16);
}

__global__ void prep(const float* __restrict__ W0, const float* __restrict__ W1,
                     const float* __restrict__ W2, const float* __restrict__ W3,
                     unsigned* __restrict__ wsu) {
  int tid = blockIdx.x * blockDim.x + threadIdx.x;
  int stride = gridDim.x * blockDim.x;
  // W0: [136][256]; W0 is [256 out][264 in]; rows k>=264 pad 0
  for (int i = tid; i < 136 * 256; i += stride) {
    int kk = i >> 8, r = i & 255, lq = r >> 2, j = r & 3;
    int k  = 2 * kk + (j >> 1);
    int c0 = 4 * lq + (j & 1) * 2;
    float lo = (k < DD) ? W0[c0 * DD + k] : 0.f;
    float hi = (k < DD) ? W0[(c0 + 1) * DD + k] : 0.f;
    wsu[WS_W0B + i] = pk2(lo, hi);
  }
  // W1/W2 [256][256], W3 main cols 0..255 (W3 is [264 out][256 in])
  for (int i = tid; i < 128 * 256; i += stride) {
    int kk = i >> 8, r = i & 255, lq = r >> 2, j = r & 3;
    int k  = 2 * kk + (j >> 1);
    int c0 = 4 * lq + (j & 1) * 2;
    wsu[WS_W1B + i] = pk2(W1[c0 * 256 + k], W1[(c0 + 1) * 256 + k]);
    wsu[WS_W2B + i] = pk2(W2[c0 * 256 + k], W2[(c0 + 1) * 256 + k]);
    wsu[WS_W3B + i] = pk2(W3[c0 * 256 + k], W3[(c0 + 1) * 256 + k]);
  }
  // W3 tail cols 256..271 (>=264 pad 0): [128][16]
  for (int i = tid; i < 128 * 16; i += stride) {
    int kk = i >> 4, r = i & 15, lq = r >> 2, j = r & 3;
    int k  = 2 * kk + (j >> 1);
    int c0 = 256 + 4 * lq + (j & 1) * 2;
    float lo = (c0 < DD) ? W3[c0 * 256 + k] : 0.f;
    float hi = (c0 + 1 < DD) ? W3[(c0 + 1) * 256 + k] : 0.f;
    wsu[WS_W3T + i] = pk2(lo, hi);
  }
}

// 1024 thr = 16 waves = 4 waves/SIMD (2x R19 latency hiding). Empirical VGPR
// grant at 1024thr is 64 (R13); R19 measured this code shape needs ~40 at
// unroll 4 -> fits. Paired-row uint4 loads: 16B/transaction, half the loads
// and half the addressing of R19's uint2 stream. Bounded unroll ONLY (full
// unroll hoists all loads -> spill -> L2 pollution; R13/14/17/18 lesson).
__global__ __launch_bounds__(NTH) void node_integrate(
    const float* __restrict__ ts, const float* __restrict__ xs,
    const float* __restrict__ a_sample,
    const float* __restrict__ b0g, const float* __restrict__ b1g,
    const float* __restrict__ b2g, const float* __restrict__ b3g,
    const unsigned* __restrict__ wsu, float* __restrict__ out) {
  extern __shared__ float sm[];
  unsigned* smu = (unsigned*)sm;
  const int b   = blockIdx.x;
  const int tid = threadIdx.x;
  const int w   = tid >> 6;    // wave 0..15
  const int l   = tid & 63;    // lane

  // ---- one-time fills ----
  for (int i = tid; i < 256; i += NTH) {
    sm[L_B0 + i] = b0g[i];
    sm[L_B1 + i] = b1g[i];
    sm[L_B2 + i] = b2g[i];
  }
  for (int i = tid; i < 272; i += NTH) sm[L_B3 + i] = (i < DD) ? b3g[i] : 0.f;
  {
    const uint4* src = (const uint4*)(wsu + WS_W1B);
    uint4* dst = (uint4*)(smu + L_W1B);
    for (int i = tid; i < 128 * 64; i += NTH) dst[i] = src[i];
  }
  {
    const float sc = a_sample[b] * expf(-0.1f * ts[0]);
    for (int i = tid; i < 272; i += NTH) {
      float v = 0.f;
      if (i < DATA) v = sc * sinf(PI_F * xs[(size_t)b * DATA + i]);
      sm[L_Y + i]  = v;
      sm[L_IN + i] = 0.f;
    }
  }
  __syncthreads();

  if (tid < DATA) out[((size_t)b * NT) * DATA + tid] = sm[L_Y + tid];

  float4* ps4 = (float4*)(sm + L_PS);                 // [16] rows of 68 float4
  const uint4* w0b4 = (const uint4*)(wsu + WS_W0B);   // [136][64] uint4
  const uint4* w2b4 = (const uint4*)(wsu + WS_W2B);   // [128][64]
  const uint4* w3b4 = (const uint4*)(wsu + WS_W3B);   // [128][64]
  const uint4* w3t4 = (const uint4*)(wsu + WS_W3T);   // [128][4]
  const uint4* w1l4 = (const uint4*)(smu + L_W1B);    // LDS [128][64]

#pragma unroll 1
  for (int t = 0; t < NT - 1; ++t) {
    const float dt = ts[t + 1] - ts[t];
    const float h  = dt * (1.0f / NSUB);
#pragma unroll 1
    for (int sub = 0; sub < NSUB; ++sub) {
#pragma unroll 1
      for (int st = 0; st < 3; ++st) {
        const float* finp = sm + ((st == 0) ? L_Y : L_IN);

        // ---- L0: hA = tanh(W0 @ fin + b0); K=272 -> 136 row-pairs
        {
          float4 acc; acc.x = acc.y = acc.z = acc.w = 0.f;
#pragma unroll 4
          for (int i = 0; i < 8; ++i) {
            const int kk = w + 16 * i;          // < 128
            const uint4 u = w0b4[kk * 64 + l];
            const float f0 = finp[2 * kk], f1 = finp[2 * kk + 1];
            FMA8(acc, u, f0, f1)
          }
          if (w < 8) {                          // kk = 128..135
            const int kk = 128 + w;
            const uint4 u = w0b4[kk * 64 + l];
            const float f0 = finp[2 * kk], f1 = finp[2 * kk + 1];
            FMA8(acc, u, f0, f1)
          }
          ps4[w * 68 + l] = acc;
        }
        __syncthreads();
        if (tid < 256) {
          float sv = sm[L_B0 + tid];
#pragma unroll
          for (int ww = 0; ww < NW; ++ww) sv += sm[L_PS + ww * 272 + tid];
          sm[L_HA + tid] = tanhf(sv);
        }
        __syncthreads();

        // ---- L1: hB = tanh(W1 @ hA + b1); all from LDS, paired uint4
        {
          float4 acc; acc.x = acc.y = acc.z = acc.w = 0.f;
#pragma unroll 4
          for (int i = 0; i < 8; ++i) {
            const int kk = w + 16 * i;          // < 128
            const uint4 u = w1l4[kk * 64 + l];
            const float f0 = sm[L_HA + 2 * kk], f1 = sm[L_HA + 2 * kk + 1];
            FMA8(acc, u, f0, f1)
          }
          ps4[w * 68 + l] = acc;
        }
        __syncthreads();
        if (tid < 256) {
          float sv = sm[L_B1 + tid];
#pragma unroll
          for (int ww = 0; ww < NW; ++ww) sv += sm[L_PS + ww * 272 + tid];
          sm[L_HB + tid] = tanhf(sv);
        }
        __syncthreads();

        // ---- L2: hA = tanh(W2 @ hB + b2); streamed paired uint4
        {
          float4 acc; acc.x = acc.y = acc.z = acc.w = 0.f;
#pragma unroll 4
          for (int i = 0; i < 8; ++i) {
            const int kk = w + 16 * i;
            const uint4 u = w2b4[kk * 64 + l];
            const float f0 = sm[L_HB + 2 * kk], f1 = sm[L_HB + 2 * kk + 1];
            FMA8(acc, u, f0, f1)
          }
          ps4[w * 68 + l] = acc;
        }
        __syncthreads();
        if (tid < 256) {
          float sv = sm[L_B2 + tid];
#pragma unroll
          for (int ww = 0; ww < NW; ++ww) sv += sm[L_PS + ww * 272 + tid];
          sm[L_HA + tid] = tanhf(sv);
        }
        __syncthreads();

        // ---- L3: kv = W3 @ hA + b3; main cols + 16-col tail
        {
          float4 acc;  acc.x = acc.y = acc.z = acc.w = 0.f;
#pragma unroll 4
          for (int i = 0; i < 8; ++i) {
            const int kk = w + 16 * i;
            const uint4 u = w3b4[kk * 64 + l];
            const float f0 = sm[L_HA + 2 * kk], f1 = sm[L_HA + 2 * kk + 1];
            FMA8(acc, u, f0, f1)
          }
          ps4[w * 68 + l] = acc;
          if (l < 4) {
            float4 accx; accx.x = accx.y = accx.z = accx.w = 0.f;
#pragma unroll 4
            for (int i = 0; i < 8; ++i) {
              const int kk = w + 16 * i;
              const uint4 u = w3t4[kk * 4 + l];
              const float f0 = sm[L_HA + 2 * kk], f1 = sm[L_HA + 2 * kk + 1];
              FMA8(accx, u, f0, f1)
            }
            ps4[w * 68 + 64 + l] = accx;
          }
        }
        __syncthreads();
        if (tid < DD) {
          float kv = sm[L_B3 + tid];
#pragma unroll
          for (int ww = 0; ww < NW; ++ww) kv += sm[L_PS + ww * 272 + tid];
          if (st == 0) {
            sm[L_ACC + tid] = (2.0f / 9.0f) * kv;
            sm[L_IN + tid]  = sm[L_Y + tid] + 0.5f * h * kv;
          } else if (st == 1) {
            sm[L_ACC + tid] += (1.0f / 3.0f) * kv;
            sm[L_IN + tid]   = sm[L_Y + tid] + 0.75f * h * kv;
          } else {
            sm[L_Y + tid] += h * (sm[L_ACC + tid] + (4.0f / 9.0f) * kv);
          }
        }
        __syncthreads();
      }
    }
    if (tid < DATA) out[((size_t)b * NT + (t + 1)) * DATA + tid] = sm[L_Y + tid];
  }
}

extern "C" void kernel_launch(void* const* d_in, const int* in_sizes, int n_in,
                              void* d_out, int out_size, void* d_ws, size_t ws_size,
                              hipStream_t stream) {
  const float* ts = (const float*)d_in[0];
  const float* xs = (const float*)d_in[1];
  const float* a  = (const float*)d_in[2];
  const float* W0 = (const float*)d_in[3];
  const float* b0 = (const float*)d_in[4];
  const float* W1 = (const float*)d_in[5];
  const float* b1 = (const float*)d_in[6];
  const float* W2 = (const float*)d_in[7];
  const float* b2 = (const float*)d_in[8];
  const float* W3 = (const float*)d_in[9];
  const float* b3 = (const float*)d_in[10];
  unsigned* ws = (unsigned*)d_ws;
  float* out = (float*)d_out;

  const size_t lds_bytes = LDS_WORDS * sizeof(float);
  hipFuncSetAttribute(reinterpret_cast<const void*>(node_integrate),
                      hipFuncAttributeMaxDynamicSharedMemorySize,
                      (int)lds_bytes);

  hipLaunchKernelGGL(prep, dim3(256), dim3(256), 0, stream, W0, W1, W2, W3, ws);
  hipLaunchKernelGGL(node_integrate, dim3(NB), dim3(NTH), lds_bytes, stream,
                     ts, xs, a, b0, b1, b2, b3, ws, out);
}

// Round 22
// 4699.661 us; speedup vs baseline: 10.7422x; 1.1685x over previous
//
#include <hip/hip_runtime.h>
#include <cmath>

#define NB   256
#define NT   64
#define DATA 256
#define DD   264
#define NSUB 4
#define NTH  1024
#define NW   16
#define PI_F 3.14159265358979323846f

typedef _Float16 h2 __attribute__((ext_vector_type(2)));
typedef __fp16   g2 __attribute__((ext_vector_type(2)));   // cvt_pkrtz return type

// ---- d_ws u32 offsets: f16 pairs ALONG K ----
// u32 at [kk][j] = { W[2kk][j], W[2kk+1][j] } as f16 (slot0 = 2kk).
#define WS_W0  0                        // [136 kk][256 j]  (K=272 padded)
#define WS_W1  (WS_W0 + 136 * 256)      // [128][256]
#define WS_W2  (WS_W1 + 128 * 256)      // [128][256]
#define WS_W3  (WS_W2 + 128 * 256)      // [128][256]  cols 0..255
#define WS_W3T (WS_W3 + 128 * 256)      // [128][16]   cols 256..271 (>=264 pad 0)

// ---- LDS word offsets ----
#define L_W1   0                        // [128 kk][256 u32] f16-pair W1 = 128 KB
#define L_PS   (L_W1 + 128 * 256)       // fp32 [16][272]
#define L_YP   (L_PS + NW * 272)        // 136 u32: packed y pairs
#define L_INP  (L_YP + 136)             // 136 u32: packed s_in pairs
#define L_HAP  (L_INP + 136)            // 128 u32: packed hA pairs
#define L_HBP  (L_HAP + 128)            // 128 u32: packed hB pairs
#define L_Y    (L_HBP + 128)            // 272 fp32 state (pads 0)
#define L_ACC  (L_Y + 272)              // 272
#define L_B0   (L_ACC + 272)            // 256
#define L_B1   (L_B0 + 256)             // 256
#define L_B2   (L_B1 + 256)             // 256
#define L_B3   (L_B2 + 256)             // 272
#define LDS_WORDS (L_B3 + 272)          // 39232 words = 156,928 B -> 1 block/CU

__device__ __forceinline__ float dot2(unsigned wu, unsigned hu, float c) {
  h2 a = __builtin_bit_cast(h2, wu);
  h2 b = __builtin_bit_cast(h2, hu);
#if __has_builtin(__builtin_amdgcn_fdot2)
  return __builtin_amdgcn_fdot2(a, b, c, false);
#else
  return c + (float)a[0] * (float)b[0] + (float)a[1] * (float)b[1];
#endif
}

__device__ __forceinline__ unsigned pkh(float a, float b) {
#if __has_builtin(__builtin_amdgcn_cvt_pkrtz)
  g2 v = __builtin_amdgcn_cvt_pkrtz(a, b);
  return __builtin_bit_cast(unsigned, v);
#else
  h2 v; v[0] = (_Float16)a; v[1] = (_Float16)b;
  return __builtin_bit_cast(unsigned, v);
#endif
}

__device__ __forceinline__ unsigned pkh_rne(float a, float b) {
  h2 v; v[0] = (_Float16)a; v[1] = (_Float16)b;   // RNE casts (prep only)
  return __builtin_bit_cast(unsigned, v);
}

// DOT4: one uint4 (4 cols x k-pair) against one packed act pair
#define DOT4(acc, u, hp)                                                      \
  acc.x = dot2(u.x, hp, acc.x);                                               \
  acc.y = dot2(u.y, hp, acc.y);                                               \
  acc.z = dot2(u.z, hp, acc.z);                                               \
  acc.w = dot2(u.w, hp, acc.w);

__global__ void prep(const float* __restrict__ W0, const float* __restrict__ W1,
                     const float* __restrict__ W2, const float* __restrict__ W3,
                     unsigned* __restrict__ wsu) {
  int tid = blockIdx.x * blockDim.x + threadIdx.x;
  int stride = gridDim.x * blockDim.x;
  // W0 [256 out][264 in]: wsu[kk*256 + j] = {W0[j][2kk], W0[j][2kk+1]}
  for (int i = tid; i < 136 * 256; i += stride) {
    int kk = i >> 8, j = i & 255;
    int k0 = 2 * kk, k1 = 2 * kk + 1;
    float lo = (k0 < DD) ? W0[j * DD + k0] : 0.f;
    float hi = (k1 < DD) ? W0[j * DD + k1] : 0.f;
    wsu[WS_W0 + i] = pkh_rne(lo, hi);
  }
  for (int i = tid; i < 128 * 256; i += stride) {   // W1, W2, W3 main
    int kk = i >> 8, j = i & 255;
    wsu[WS_W1 + i] = pkh_rne(W1[j * 256 + 2 * kk], W1[j * 256 + 2 * kk + 1]);
    wsu[WS_W2 + i] = pkh_rne(W2[j * 256 + 2 * kk], W2[j * 256 + 2 * kk + 1]);
    wsu[WS_W3 + i] = pkh_rne(W3[j * 256 + 2 * kk], W3[j * 256 + 2 * kk + 1]);
  }
  // W3 tail cols 256..271 (>=264 pad 0): [128][16]
  for (int i = tid; i < 128 * 16; i += stride) {
    int kk = i >> 4, c = 256 + (i & 15);
    float lo = (c < DD) ? W3[c * 256 + 2 * kk] : 0.f;
    float hi = (c < DD) ? W3[c * 256 + 2 * kk + 1] : 0.f;
    wsu[WS_W3T + i] = pkh_rne(lo, hi);
  }
}

// R21 = R20 structure + v_dot2_f32_f16 data path: weights/activations as f16
// pairs along k -> inner iter = 1 load + 1 LDS broadcast + 4 dot2 (~8 inst)
// vs R20's 8 FMA + 8 unpack (~19 inst). Bounded unroll 4 ONLY (full unroll
// hoists loads -> spill -> L2 pollution; R13/14/17/18). f16 (10-bit mantissa)
// beats bf16 (7-bit) accuracy.
__global__ __launch_bounds__(NTH) void node_integrate(
    const float* __restrict__ ts, const float* __restrict__ xs,
    const float* __restrict__ a_sample,
    const float* __restrict__ b0g, const float* __restrict__ b1g,
    const float* __restrict__ b2g, const float* __restrict__ b3g,
    const unsigned* __restrict__ wsu, float* __restrict__ out) {
  extern __shared__ float sm[];
  unsigned* smu = (unsigned*)sm;
  const int b   = blockIdx.x;
  const int tid = threadIdx.x;
  const int w   = tid >> 6;    // wave 0..15
  const int l   = tid & 63;    // lane

  // ---- one-time fills ----
  for (int i = tid; i < 256; i += NTH) {
    sm[L_B0 + i] = b0g[i];
    sm[L_B1 + i] = b1g[i];
    sm[L_B2 + i] = b2g[i];
  }
  for (int i = tid; i < 272; i += NTH) sm[L_B3 + i] = (i < DD) ? b3g[i] : 0.f;
  {
    const uint4* src = (const uint4*)(wsu + WS_W1);
    uint4* dst = (uint4*)(smu + L_W1);
    for (int i = tid; i < 128 * 64; i += NTH) dst[i] = src[i];
  }
  {
    const float sc = a_sample[b] * expf(-0.1f * ts[0]);
    for (int i = tid; i < 272; i += NTH) {
      float v = 0.f;
      if (i < DATA) v = sc * sinf(PI_F * xs[(size_t)b * DATA + i]);
      sm[L_Y + i] = v;
    }
  }
  __syncthreads();
  // pack y pairs; s_in packed = 0 init (incl. pads)
  if (tid < 136) {
    smu[L_YP + tid]  = pkh(sm[L_Y + 2 * tid], sm[L_Y + 2 * tid + 1]);
    smu[L_INP + tid] = 0u;
  }
  __syncthreads();

  if (tid < DATA) out[((size_t)b * NT) * DATA + tid] = sm[L_Y + tid];

  float4* ps4 = (float4*)(sm + L_PS);                 // [16] rows of 68 float4
  const uint4* w0b4 = (const uint4*)(wsu + WS_W0);    // [136][64] uint4
  const uint4* w2b4 = (const uint4*)(wsu + WS_W2);    // [128][64]
  const uint4* w3b4 = (const uint4*)(wsu + WS_W3);    // [128][64]
  const uint4* w3t4 = (const uint4*)(wsu + WS_W3T);   // [128][4]
  const uint4* w1l4 = (const uint4*)(smu + L_W1);     // LDS [128][64]

#pragma unroll 1
  for (int t = 0; t < NT - 1; ++t) {
    const float dt = ts[t + 1] - ts[t];
    const float h  = dt * (1.0f / NSUB);
#pragma unroll 1
    for (int sub = 0; sub < NSUB; ++sub) {
#pragma unroll 1
      for (int st = 0; st < 3; ++st) {
        const unsigned* finp = smu + ((st == 0) ? L_YP : L_INP);

        // ---- L0: hA = tanh(W0 @ fin + b0); K=272 -> 136 k-pairs
        {
          float4 acc; acc.x = acc.y = acc.z = acc.w = 0.f;
#pragma unroll 4
          for (int i = 0; i < 8; ++i) {
            const int kk = w + 16 * i;          // < 128
            const uint4 u = w0b4[kk * 64 + l];
            const unsigned hp = finp[kk];
            DOT4(acc, u, hp)
          }
          if (w < 8) {                          // kk = 128..135
            const int kk = 128 + w;
            const uint4 u = w0b4[kk * 64 + l];
            const unsigned hp = finp[kk];
            DOT4(acc, u, hp)
          }
          ps4[w * 68 + l] = acc;
        }
        __syncthreads();
        if (tid < 256) {
          float sv = sm[L_B0 + tid];
#pragma unroll
          for (int ww = 0; ww < NW; ++ww) sv += sm[L_PS + ww * 272 + tid];
          const float hv = tanhf(sv);
          const float ho = __shfl_xor(hv, 1);
          if (!(tid & 1)) smu[L_HAP + (tid >> 1)] = pkh(hv, ho);
        }
        __syncthreads();

        // ---- L1: hB = tanh(W1 @ hA + b1); all from LDS
        {
          float4 acc; acc.x = acc.y = acc.z = acc.w = 0.f;
#pragma unroll 4
          for (int i = 0; i < 8; ++i) {
            const int kk = w + 16 * i;          // < 128
            const uint4 u = w1l4[kk * 64 + l];
            const unsigned hp = smu[L_HAP + kk];
            DOT4(acc, u, hp)
          }
          ps4[w * 68 + l] = acc;
        }
        __syncthreads();
        if (tid < 256) {
          float sv = sm[L_B1 + tid];
#pragma unroll
          for (int ww = 0; ww < NW; ++ww) sv += sm[L_PS + ww * 272 + tid];
          const float hv = tanhf(sv);
          const float ho = __shfl_xor(hv, 1);
          if (!(tid & 1)) smu[L_HBP + (tid >> 1)] = pkh(hv, ho);
        }
        __syncthreads();

        // ---- L2: hA = tanh(W2 @ hB + b2); streamed
        {
          float4 acc; acc.x = acc.y = acc.z = acc.w = 0.f;
#pragma unroll 4
          for (int i = 0; i < 8; ++i) {
            const int kk = w + 16 * i;
            const uint4 u = w2b4[kk * 64 + l];
            const unsigned hp = smu[L_HBP + kk];
            DOT4(acc, u, hp)
          }
          ps4[w * 68 + l] = acc;
        }
        __syncthreads();
        if (tid < 256) {
          float sv = sm[L_B2 + tid];
#pragma unroll
          for (int ww = 0; ww < NW; ++ww) sv += sm[L_PS + ww * 272 + tid];
          const float hv = tanhf(sv);
          const float ho = __shfl_xor(hv, 1);
          if (!(tid & 1)) smu[L_HAP + (tid >> 1)] = pkh(hv, ho);
        }
        __syncthreads();

        // ---- L3: kv = W3 @ hA + b3; main cols + 16-col tail
        {
          float4 acc; acc.x = acc.y = acc.z = acc.w = 0.f;
#pragma unroll 4
          for (int i = 0; i < 8; ++i) {
            const int kk = w + 16 * i;
            const uint4 u = w3b4[kk * 64 + l];
            const unsigned hp = smu[L_HAP + kk];
            DOT4(acc, u, hp)
          }
          ps4[w * 68 + l] = acc;
          if (l < 4) {
            float4 accx; accx.x = accx.y = accx.z = accx.w = 0.f;
#pragma unroll 4
            for (int i = 0; i < 8; ++i) {
              const int kk = w + 16 * i;
              const uint4 u = w3t4[kk * 4 + l];
              const unsigned hp = smu[L_HAP + kk];
              DOT4(accx, u, hp)
            }
            ps4[w * 68 + 64 + l] = accx;
          }
        }
        __syncthreads();
        // ---- reduce + RK + repack fin ----
        if (tid < DD) {
          float kv = sm[L_B3 + tid];
#pragma unroll
          for (int ww = 0; ww < NW; ++ww) kv += sm[L_PS + ww * 272 + tid];
          float val;
          if (st == 0) {
            sm[L_ACC + tid] = (2.0f / 9.0f) * kv;
            val = sm[L_Y + tid] + 0.5f * h * kv;
          } else if (st == 1) {
            sm[L_ACC + tid] += (1.0f / 3.0f) * kv;
            val = sm[L_Y + tid] + 0.75f * h * kv;
          } else {
            val = sm[L_Y + tid] + h * (sm[L_ACC + tid] + (4.0f / 9.0f) * kv);
            sm[L_Y + tid] = val;
          }
          const float vo = __shfl_xor(val, 1);
          if (!(tid & 1)) {
            const int dst = (st == 2) ? L_YP : L_INP;
            smu[dst + (tid >> 1)] = pkh(val, vo);
          }
        }
        __syncthreads();
      }
    }
    if (tid < DATA) out[((size_t)b * NT + (t + 1)) * DATA + tid] = sm[L_Y + tid];
  }
}

extern "C" void kernel_launch(void* const* d_in, const int* in_sizes, int n_in,
                              void* d_out, int out_size, void* d_ws, size_t ws_size,
                              hipStream_t stream) {
  const float* ts = (const float*)d_in[0];
  const float* xs = (const float*)d_in[1];
  const float* a  = (const float*)d_in[2];
  const float* W0 = (const float*)d_in[3];
  const float* b0 = (const float*)d_in[4];
  const float* W1 = (const float*)d_in[5];
  const float* b1 = (const float*)d_in[6];
  const float* W2 = (const float*)d_in[7];
  const float* b2 = (const float*)d_in[8];
  const float* W3 = (const float*)d_in[9];
  const float* b3 = (const float*)d_in[10];
  unsigned* ws = (unsigned*)d_ws;
  float* out = (float*)d_out;

  const size_t lds_bytes = LDS_WORDS * sizeof(float);
  (void)hipFuncSetAttribute(reinterpret_cast<const void*>(node_integrate),
                            hipFuncAttributeMaxDynamicSharedMemorySize,
                            (int)lds_bytes);

  hipLaunchKernelGGL(prep, dim3(256), dim3(256), 0, stream, W0, W1, W2, W3, ws);
  hipLaunchKernelGGL(node_integrate, dim3(NB), dim3(NTH), lds_bytes, stream,
                     ts, xs, a, b0, b1, b2, b3, ws, out);
}